// Round 6
// baseline (148.556 us; speedup 1.0000x reference)
//
#include <hip/hip_runtime.h>

// Zero-phase bandpass FIR = one 8191-tap correlation with the kernel
// autocorrelation g, as an implicit-Toeplitz MFMA GEMM.
//   out[t] = sum_s g[s] * xe[t + s],  g = autocorr(k) (bf16, hi only)
// Round 11: de-serialize wave arbitration. (1) s_setprio REMOVED -- at
// 2 waves/SIMD a prio-1 MFMA burst starves the partner wave's load issue,
// phase-locking the two waves into alternating MFMA/load instead of
// overlap (suspected cause of the invariant ~40% MfmaUtil). (2) B-prefetch
// interleaved INTO the burst at r-cluster granularity + A ring update
// between clusters (wave is self-overlapping, no partner needed).
// (3) chunk-boundary vmcnt(0) -> vmcnt(8): drains only the 4 staging
// loads (in-order VMEM retirement), leaves the 8 fresh A-loads in flight.

#define T_LEN   131072
#define XE_LEN  139776
#define XE_U4   (XE_LEN / 8)      // 17472 uint4 per row
#define QQ      72                // Q-steps per wave (per Q-quarter)
#define NCH     9                 // chunks per wave
#define GP_STRIDE 24576           // bytes per gpad copy

typedef float  f32x4  __attribute__((ext_vector_type(4)));
typedef __bf16 bf16x8 __attribute__((ext_vector_type(8)));

// ---------- ws layout (bytes) ----------
#define WS_KZ   0                 // 12288 floats (zero-padded k)
#define WS_G    49152             // 8192 floats  (autocorrelation)
#define WS_GP   81920             // 2 copies x 24576 B bf16 gpad
#define WS_XE   131072            // 32*139776 bf16 padded signal
#define WS_END  9347072

__device__ __forceinline__ void gload_lds16(const uint4* g, uint4* lds) {
  __builtin_amdgcn_global_load_lds(
      (const __attribute__((address_space(1))) unsigned int*)g,
      (__attribute__((address_space(3))) unsigned int*)lds, 16, 0, 0);
}

// K1: g[s] += partial over 256-long i-chunk; grid (32, 16).
__global__ void k_autocorr(const float* __restrict__ k,
                           const float* __restrict__ kz,
                           float* __restrict__ g) {
  int s = blockIdx.x * 256 + threadIdx.x;
  int i0 = blockIdx.y * 256;
  const float* kk  = k + i0;
  const float* kzs = kz + (8191 - s) + i0;   // 4-B aligned only
  float a0 = 0.f, a1 = 0.f, a2 = 0.f, a3 = 0.f;
  #pragma unroll 4
  for (int i = 0; i < 256; i += 4) {
    float4 kv = *(const float4*)(kk + i);
    float4 zv;
    __builtin_memcpy(&zv, kzs + i, 16);
    a0 = fmaf(kv.x, zv.x, a0);
    a1 = fmaf(kv.y, zv.y, a1);
    a2 = fmaf(kv.z, zv.z, a2);
    a3 = fmaf(kv.w, zv.w, a3);
  }
  atomicAdd(&g[s], (a0 + a1) + (a2 + a3));
}

// K2': gpad[e] = bf16(g[e]) for e in [0,8190], else 0, over e in
// [-1024, 10240); TWO copies byte-shifted by GP_STRIDE+2 so every lane's
// 16-B A-frag read (start element 32(F-24)+8q-n, parity = n&1) is 4-B
// aligned. Grid (44), 256 thr.
__global__ void k_build_gpad(const float* __restrict__ g,
                             char* __restrict__ gp) {
  int idx = blockIdx.x * 256 + threadIdx.x;   // [0, 11264)
  int e = idx - 1024;
  float v = (e >= 0 && e <= 8190) ? g[e] : 0.0f;
  __bf16 b = (__bf16)v;
  *(__bf16*)(gp + 2 * idx) = b;
  *(__bf16*)(gp + GP_STRIDE + 2 + 2 * idx) = b;
}

// K0 (fused): xe[row][w] = bf16( X(w-4095) ), reflect in [-2048, T+2048),
// else 0. blockIdx.y==0 additionally builds kz (zero-padded k) and zeros g.
__global__ void k_build_xe(const float* __restrict__ x, __bf16* __restrict__ xe,
                           const float* __restrict__ k, float* __restrict__ kz,
                           float* __restrict__ g) {
  if (blockIdx.y == 0) {           // fused former k_build_kz
    int m = blockIdx.x * 256 + threadIdx.x;
    if (m < 12288) {
      int i = m - 4096;
      kz[m] = (i >= 0 && i < 4096) ? k[i] : 0.0f;
    }
    if (m < 8192) g[m] = 0.0f;
  }
  int e0 = (blockIdx.x * 256 + threadIdx.x) * 8;
  int row = blockIdx.y;
  if (e0 >= XE_LEN) return;
  const float* xr = x + (size_t)row * T_LEN;
  int v0 = e0 - 4095;
  bf16x8 outv;
  if (v0 >= 0 && v0 <= T_LEN - 8) {
    float4 f0, f1;
    __builtin_memcpy(&f0, xr + v0, 16);
    __builtin_memcpy(&f1, xr + v0 + 4, 16);
    outv[0] = (__bf16)f0.x; outv[1] = (__bf16)f0.y;
    outv[2] = (__bf16)f0.z; outv[3] = (__bf16)f0.w;
    outv[4] = (__bf16)f1.x; outv[5] = (__bf16)f1.y;
    outv[6] = (__bf16)f1.z; outv[7] = (__bf16)f1.w;
  } else {
    #pragma unroll
    for (int u = 0; u < 8; ++u) {
      int v = v0 + u;
      float val = 0.0f;
      if (v >= -2048 && v < T_LEN + 2048) {
        int v2 = v < 0 ? -v : v;
        v2 = v2 >= T_LEN ? 2 * T_LEN - 2 - v2 : v2;
        val = xr[v2];
      }
      outv[u] = (__bf16)val;
    }
  }
  ((uint4*)(xe + (size_t)row * XE_LEN))[e0 >> 3] =
      __builtin_bit_cast(uint4, outv);
}

// One pipelined Q-step, r-cluster interleaved: per r, prefetch next step's
// B-frag (BN[r]) from LDS, then 4 MFMAs on this step's BC[r]. A ring
// update (1 global load, L1-resident gpad) issued before cluster 0, its
// result consumed next chunk (latency-free). No setprio.
#define QSTEP(CH, Qr, GA, GB, GC, GD, BC, BN)                              \
  {                                                                        \
    bf16x8 a3 = GA[Qr], a2 = GB[Qr], a1 = GC[Qr], a0 = GD[Qr];             \
    uint4 tmp;                                                             \
    __builtin_memcpy(&tmp,                                                 \
        laneA + ((size_t)(Qbeg + (CH) * 8 + 32 + Qr) << 6), 16);           \
    GA[Qr] = __builtin_bit_cast(bf16x8, tmp);                              \
    _Pragma("unroll")                                                      \
    for (int r = 0; r < 4; ++r) {                                          \
      if ((Qr) < 7)              /* prefetch next step's B under MFMAs */  \
        BN[r] = __builtin_bit_cast(bf16x8, bw[(r << 6) + 4 * ((Qr) + 1)]); \
      acc[r][0] = __builtin_amdgcn_mfma_f32_16x16x32_bf16(a0, BC[r],       \
                                                          acc[r][0], 0, 0, 0); \
      acc[r][1] = __builtin_amdgcn_mfma_f32_16x16x32_bf16(a1, BC[r],       \
                                                          acc[r][1], 0, 0, 0); \
      acc[r][2] = __builtin_amdgcn_mfma_f32_16x16x32_bf16(a2, BC[r],       \
                                                          acc[r][2], 0, 0, 0); \
      acc[r][3] = __builtin_amdgcn_mfma_f32_16x16x32_bf16(a3, BC[r],       \
                                                          acc[r][3], 0, 0, 0); \
    }                                                                      \
  }

// One chunk (8 Q-steps), ring roles GA=oldest(mt3) .. GD=newest(mt0).
// Staging of chunk CH+1 issued at top. Boundary wait is vmcnt(8): VMEM
// retires in order, so <=8 outstanding <=> the 4 staging loads (oldest)
// are done; the 8 fresh A-loads stay in flight (compiler inserts its own
// counted waits before their next-chunk consumption).
#define CHUNK(CH, BUF, GA, GB, GC, GD, DO_STAGE)                           \
  {                                                                        \
    if (DO_STAGE) {                                                        \
      uint4* dst = sw + ((BUF ^ 1) << 8);                                  \
      const uint4* src = gbase + (((CH) + 1) << 5);                        \
      _Pragma("unroll")                                                    \
      for (int r = 0; r < 4; ++r)                                          \
        gload_lds16(src + (size_t)r * XE_U4, dst + (r << 6));              \
    }                                                                      \
    const uint4* bw = sw + ((BUF) << 8) + lofs;                            \
    bf16x8 B0[4], B1[4];                                                   \
    _Pragma("unroll")                                                      \
    for (int r = 0; r < 4; ++r)                                            \
      B0[r] = __builtin_bit_cast(bf16x8, bw[r << 6]);                      \
    QSTEP(CH, 0, GA, GB, GC, GD, B0, B1)                                   \
    QSTEP(CH, 1, GA, GB, GC, GD, B1, B0)                                   \
    QSTEP(CH, 2, GA, GB, GC, GD, B0, B1)                                   \
    QSTEP(CH, 3, GA, GB, GC, GD, B1, B0)                                   \
    QSTEP(CH, 4, GA, GB, GC, GD, B0, B1)                                   \
    QSTEP(CH, 5, GA, GB, GC, GD, B1, B0)                                   \
    QSTEP(CH, 6, GA, GB, GC, GD, B0, B1)                                   \
    QSTEP(CH, 7, GA, GB, GC, GD, B1, B0)                                   \
    if (DO_STAGE)                                                          \
      asm volatile("s_waitcnt vmcnt(8)" ::: "memory");                     \
  }

// Main: 512 threads = 8 waves = 2 row-groups (4 rows) x 4 Q-quarters.
// Per Q-step: 1 fresh A load (gpad, L1), 4 ds_read_b128 (B, prefetched
// one step ahead inside the MFMA clusters), 16 MFMA. Ring G0..G3 rotates
// roles every chunk. No barriers, no setprio in the main loop.
__global__ __launch_bounds__(512, 2) void k_fir_mfma(
    const uint4* __restrict__ xeu, const char* __restrict__ gpad,
    float* __restrict__ out) {
  __shared__ uint4 sbB[4096];      // 64 KB: wave*512 + buf*256 + row*64

  const int tid = threadIdx.x;
  const int w   = tid >> 6;                  // 8 waves
  const int l   = tid & 63;
  const int q   = l >> 4;
  const int n   = l & 15;
  const int qh  = w & 3;                     // Q-quarter
  const int rg  = w >> 2;                    // row-group (4 rows)

  // XCD swizzle: 512 blocks, 8 XCDs -> 64 contiguous flat ids per XCD.
  const int orig = blockIdx.x;
  const int flat = (orig & 7) * 64 + (orig >> 3);
  const int bx   = flat & 127;
  const int by   = flat >> 7;

  const int t0     = bx << 10;               // 1024 outputs per block
  const int brbase = by << 3;                // block's 8 rows
  const int wrbase = brbase + (rg << 2);     // this wave's 4 rows
  const int Qbeg   = qh * QQ;
  const int lofs   = q + 2 * n;              // uint4 offset in B window

  // per-lane global base for staging (lane l covers uint4 slot l of a row)
  const uint4* gbase = xeu + (size_t)wrbase * XE_U4 + (t0 >> 3) + 4 * Qbeg + l;
  uint4* sw = sbB + (w << 9);                // 512 uint4 per wave

  // A-frag source: element e0(F) = 32(F-24) + 8q - n, byte = 2(e0+1024)
  // in copy (n&1): laneA + 64F with laneA = copy_base + 16q - 2n + 512.
  const char* laneA = gpad + ((n & 1) ? (GP_STRIDE + 2) : 0)
                      + 16 * q - 2 * n + 512;

  f32x4 acc[4][4];
  #pragma unroll
  for (int r = 0; r < 4; ++r)
    #pragma unroll
    for (int m = 0; m < 4; ++m) acc[r][m] = (f32x4){0.f, 0.f, 0.f, 0.f};

  // prologue: prime ring with frags Qbeg..Qbeg+31; stage chunk 0; drain.
  bf16x8 G0[8], G1[8], G2[8], G3[8];
  #pragma unroll
  for (int j = 0; j < 8; ++j) {
    uint4 u0, u1, u2, u3;
    __builtin_memcpy(&u0, laneA + ((size_t)(Qbeg + j) << 6), 16);
    __builtin_memcpy(&u1, laneA + ((size_t)(Qbeg + 8 + j) << 6), 16);
    __builtin_memcpy(&u2, laneA + ((size_t)(Qbeg + 16 + j) << 6), 16);
    __builtin_memcpy(&u3, laneA + ((size_t)(Qbeg + 24 + j) << 6), 16);
    G0[j] = __builtin_bit_cast(bf16x8, u0);
    G1[j] = __builtin_bit_cast(bf16x8, u1);
    G2[j] = __builtin_bit_cast(bf16x8, u2);
    G3[j] = __builtin_bit_cast(bf16x8, u3);
  }
  #pragma unroll
  for (int r = 0; r < 4; ++r)
    gload_lds16(gbase + (size_t)r * XE_U4, sw + (r << 6));
  asm volatile("s_waitcnt vmcnt(0)" ::: "memory");

  CHUNK(0, 0, G0, G1, G2, G3, 1)
  CHUNK(1, 1, G1, G2, G3, G0, 1)
  CHUNK(2, 0, G2, G3, G0, G1, 1)
  CHUNK(3, 1, G3, G0, G1, G2, 1)
  CHUNK(4, 0, G0, G1, G2, G3, 1)
  CHUNK(5, 1, G1, G2, G3, G0, 1)
  CHUNK(6, 0, G2, G3, G0, G1, 1)
  CHUNK(7, 1, G3, G0, G1, G2, 1)
  CHUNK(8, 0, G0, G1, G2, G3, 0)

  // ---- combine 4 qh partials per row-group in LDS (phased mt slices) ----
  __syncthreads();
  float* C = (float*)sbB;                    // 8 rows x 1024 t (32 KB)
  const int co = (q << 2) + (n << 4);        // C/D: col=n, row=(q*4+reg)
  #pragma unroll
  for (int ph = 0; ph < 4; ++ph) {
    const int mt = (qh + ph) & 3;
    float* cp = C + ((rg << 2) << 10) + (mt << 8) + co;
    if (ph == 0) {
      #pragma unroll
      for (int r = 0; r < 4; ++r)
        *(f32x4*)(cp + (r << 10)) = acc[r][mt];
    } else {
      #pragma unroll
      for (int r = 0; r < 4; ++r) {
        f32x4 v = *(f32x4*)(cp + (r << 10));
        v += acc[r][mt];
        *(f32x4*)(cp + (r << 10)) = v;
      }
    }
    __syncthreads();
  }

  // ---- coalesced store: 2048 f32x4, 512 threads x 4 ----
  #pragma unroll
  for (int u = 0; u < 4; ++u) {
    const int idx = tid + (u << 9);
    f32x4 v = ((f32x4*)C)[idx];
    const int row = idx >> 8;                // 256 f32x4 per row
    const int tc  = (idx & 255) << 2;
    *(f32x4*)(out + (size_t)(brbase + row) * T_LEN + t0 + tc) = v;
  }
}

extern "C" void kernel_launch(void* const* d_in, const int* in_sizes, int n_in,
                              void* d_out, int out_size, void* d_ws, size_t ws_size,
                              hipStream_t stream) {
  const float* x = (const float*)d_in[0];
  const float* k = (const float*)d_in[1];
  float* out = (float*)d_out;
  char* ws = (char*)d_ws;
  if (ws_size < (size_t)WS_END) return;

  float* kz = (float*)(ws + WS_KZ);
  float* g  = (float*)(ws + WS_G);
  char*  gp = ws + WS_GP;
  __bf16* xe = (__bf16*)(ws + WS_XE);

  k_build_xe<<<dim3((XE_LEN / 8 + 255) / 256, 32), dim3(256), 0, stream>>>(
      x, xe, k, kz, g);
  k_autocorr<<<dim3(32, 16), dim3(256), 0, stream>>>(k, kz, g);
  k_build_gpad<<<dim3(44), dim3(256), 0, stream>>>(g, gp);
  k_fir_mfma<<<dim3(512), dim3(512), 0, stream>>>(
      (const uint4*)xe, gp, out);
}